// Round 11
// baseline (1344.918 us; speedup 1.0000x reference)
//
#include <hip/hip_runtime.h>

#define HW 4096   // 64*64 pixels per (b,c) image

typedef float f4 __attribute__((ext_vector_type(4)));

// ---------------------------------------------------------------------------
// proj v9 (reps-instrumented on proj ONLY): q=Wq@x, k=Wk@x, v=Wv@y.
// grid = 768 x 256 (3 blocks/CU). Family = blockIdx>>8 (0=q,1=k,2=v);
// slice = blockIdx&255 -> DISJOINT 64-px slice x all 64 couts of one matrix.
// Input HBM traffic compulsory: x read 2x (q,k fams), y 1x = 12 MB total.
// Weights staged once in LDS (64 rows x 68 stride, 17.4 KB): main-loop
// weight reads are ds_read_b128 with 8 distinct addrs/wave -> 2-way bank
// aliasing = free (m136); R9 measured ZERO conflicts for this path.
// Thread = 8 px (2xf4) x 2 couts (v7's proven shape). Per cb (4 cin):
// 8 global f4 + 2 ds_read_b128 vs 64 v_fmac. ~65 VGPR, no spill.
// reps: measurement amplification past the ~42us profiler cutoff —
// idempotent (same stores each rep); no __restrict__ so the rep loop
// cannot be hoisted (qkv may alias inputs as far as the compiler knows).
// ---------------------------------------------------------------------------
__global__ __launch_bounds__(256, 3) void proj_kernel(
    const float* x, const float* y,
    const float* Wq, const float* Wk, const float* Wv,
    float* qkv, int reps)
{
    __shared__ float wlds[64 * 68];          // 17.4 KB
    const int t   = threadIdx.x;
    const int fam = blockIdx.x >> 8;         // 0=q 1=k 2=v (uniform)
    const int sl  = blockIdx.x & 255;        // 64-px slice

    {   // stage this family's weight matrix: 64 rows x 16 f4
        const float* W = (fam == 0) ? Wq : (fam == 1) ? Wk : Wv;
#pragma unroll
        for (int s = 0; s < 4; ++s) {
            const int fi  = s * 256 + t;
            const int row = fi >> 4, c4 = fi & 15;
            const f4 w = *(const f4*)&W[row * 64 + c4 * 4];
            *(f4*)&wlds[row * 68 + c4 * 4] = w;
        }
    }
    __syncthreads();

    const int pxg = t & 7;                   // 8-px group within slice
    const int rp  = t >> 3;                  // cout-pair 0..31
    const int px0 = sl * 64 + pxg * 8;
    const int b   = px0 >> 12;
    const int pp  = px0 & 4095;
    const float* src = (fam == 2) ? y : x;   // uniform
    const float* sb  = src + (size_t)b * 64 * HW + pp;
    float* dst = qkv + ((size_t)fam << 20)
                     + ((size_t)b * 64 + rp * 2) * HW + pp;

    for (int rep = 0; rep < reps; ++rep) {
        f4 acc[2][2];                        // [cout-sub][px-half]
#pragma unroll
        for (int i = 0; i < 2; ++i)
#pragma unroll
            for (int h = 0; h < 2; ++h) acc[i][h] = (f4){0.f, 0.f, 0.f, 0.f};

#pragma unroll
        for (int cb = 0; cb < 16; ++cb) {    // 16 chunks of 4 input channels
            f4 xv[4][2];
#pragma unroll
            for (int c2 = 0; c2 < 4; ++c2) {
                xv[c2][0] = *(const f4*)&sb[(cb * 4 + c2) * HW];
                xv[c2][1] = *(const f4*)&sb[(cb * 4 + c2) * HW + 4];
            }
            const f4 w0 = *(const f4*)&wlds[(rp * 2)     * 68 + cb * 4];
            const f4 w1 = *(const f4*)&wlds[(rp * 2 + 1) * 68 + cb * 4];
#pragma unroll
            for (int c2 = 0; c2 < 4; ++c2)
#pragma unroll
                for (int h = 0; h < 2; ++h) {
                    acc[0][h] += xv[c2][h] * w0[c2];
                    acc[1][h] += xv[c2][h] * w1[c2];
                }
        }

        *(f4*)&dst[0]      = acc[0][0];
        *(f4*)&dst[4]      = acc[0][1];
        *(f4*)&dst[HW]     = acc[1][0];
        *(f4*)&dst[HW + 4] = acc[1][1];
    }
}

// ---------------------------------------------------------------------------
// attn (final form: R8/R9-proven body, reps removed, __restrict__ restored):
// per-channel 7x7 window attention, LDS k/v tile with zero halo.
// Inner op: fma + exp2 + add + fma. No clamp (|log2e*q*(k+bias)| < ~100
// << 128 -> exp2 overflow impossible). ~8us measured (R9, 14 reps).
// ---------------------------------------------------------------------------
__global__ __launch_bounds__(256) void attn_kernel(
    const float* __restrict__ qg, const float* __restrict__ kg,
    const float* __restrict__ vg,
    const float* __restrict__ rel_h, const float* __restrict__ rel_w,
    float* __restrict__ out)
{
    __shared__ float kT[22 * 72];
    __shared__ float vT[22 * 72];

    const int blk = blockIdx.x;
    const int bc  = blk >> 2;            // b*64 + c
    const int h0  = (blk & 3) << 4;
    const int c   = bc & 63;
    const int t   = threadIdx.x;

    const float* kimg = kg + (size_t)bc * HW;
    const float* vimg = vg + (size_t)bc * HW;
    const f4 z4 = {0.f, 0.f, 0.f, 0.f};

    if (t < 88) {                        // horizontal halo zero
        const int row = t >> 2, side = (t >> 1) & 1, arr = t & 1;
        float* dstl = arr ? vT : kT;
        *(f4*)&dstl[row * 72 + side * 68] = z4;
    }
#pragma unroll
    for (int j = 0; j < 2; ++j) {        // interior: 22 rows x 16 f4 chunks
        const int idx = j * 256 + t;
        if (idx < 352) {
            const int row = idx >> 4, ch = idx & 15;
            const int hy = h0 - 3 + row;
            const bool rv = ((unsigned)hy < 64u);
            const f4 kv = rv ? *(const f4*)&kimg[hy * 64 + ch * 4] : z4;
            const f4 vv = rv ? *(const f4*)&vimg[hy * 64 + ch * 4] : z4;
            *(f4*)&kT[row * 72 + ch * 4 + 4] = kv;
            *(f4*)&vT[row * 72 + ch * 4 + 4] = vv;
        }
    }
    __syncthreads();

    const int r  = t >> 4;               // 0..15
    const int w0 = (t & 15) << 2;
    const int h  = h0 + r;

    const float LOG2E = 1.4426950408889634f;
    const f4 qv = *(const f4*)&qg[(size_t)bc * HW + h * 64 + w0];
    float qe[4];
#pragma unroll
    for (int p = 0; p < 4; ++p) qe[p] = qv[p] * LOG2E;

    float qb[7][4];
    if (c < 32) {
#pragma unroll
        for (int a = 0; a < 7; ++a) {
            const float bb = rel_h[c * 7 + a];
#pragma unroll
            for (int p = 0; p < 4; ++p) qb[a][p] = qe[p] * bb;
        }
    } else {
#pragma unroll
        for (int j = 0; j < 7; ++j) {
            const float bb = rel_w[(c - 32) * 7 + j];
#pragma unroll
            for (int p = 0; p < 4; ++p) qb[j][p] = qe[p] * bb;
        }
    }

    float l[4] = {0.f, 0.f, 0.f, 0.f};
    float o[4] = {0.f, 0.f, 0.f, 0.f};

    if (c < 32) {
#pragma unroll
        for (int a = 0; a < 7; ++a) {
            const int ro = (r + a) * 72 + w0;
            const f4 k0 = *(const f4*)&kT[ro];
            const f4 k1 = *(const f4*)&kT[ro + 4];
            const f4 k2 = *(const f4*)&kT[ro + 8];
            const f4 v0 = *(const f4*)&vT[ro];
            const f4 v1 = *(const f4*)&vT[ro + 4];
            const f4 v2 = *(const f4*)&vT[ro + 8];
            const float kw[12] = {k0[0], k0[1], k0[2], k0[3], k1[0], k1[1], k1[2], k1[3],
                                  k2[0], k2[1], k2[2], k2[3]};
            const float vw[12] = {v0[0], v0[1], v0[2], v0[3], v1[0], v1[1], v1[2], v1[3],
                                  v2[0], v2[1], v2[2], v2[3]};
#pragma unroll
            for (int b2 = 0; b2 < 7; ++b2)
#pragma unroll
                for (int p = 0; p < 4; ++p) {
                    const float s = fmaf(qe[p], kw[p + b2 + 1], qb[a][p]);
                    const float e = __builtin_amdgcn_exp2f(s);
                    l[p] += e;
                    o[p] = fmaf(e, vw[p + b2 + 1], o[p]);
                }
        }
    } else {
#pragma unroll
        for (int a = 0; a < 7; ++a) {
            const int ro = (r + a) * 72 + w0;
            const f4 k0 = *(const f4*)&kT[ro];
            const f4 k1 = *(const f4*)&kT[ro + 4];
            const f4 k2 = *(const f4*)&kT[ro + 8];
            const f4 v0 = *(const f4*)&vT[ro];
            const f4 v1 = *(const f4*)&vT[ro + 4];
            const f4 v2 = *(const f4*)&vT[ro + 8];
            const float kw[12] = {k0[0], k0[1], k0[2], k0[3], k1[0], k1[1], k1[2], k1[3],
                                  k2[0], k2[1], k2[2], k2[3]};
            const float vw[12] = {v0[0], v0[1], v0[2], v0[3], v1[0], v1[1], v1[2], v1[3],
                                  v2[0], v2[1], v2[2], v2[3]};
#pragma unroll
            for (int b2 = 0; b2 < 7; ++b2)
#pragma unroll
                for (int p = 0; p < 4; ++p) {
                    const float s = fmaf(qe[p], kw[p + b2 + 1], qb[b2][p]);
                    const float e = __builtin_amdgcn_exp2f(s);
                    l[p] += e;
                    o[p] = fmaf(e, vw[p + b2 + 1], o[p]);
                }
        }
    }

    f4 res;
#pragma unroll
    for (int p = 0; p < 4; ++p)
        res[p] = o[p] * __builtin_amdgcn_rcpf(l[p]);
    *(f4*)&out[(size_t)bc * HW + h * 64 + w0] = res;
}

// ---------------------------------------------------------------------------
extern "C" void kernel_launch(void* const* d_in, const int* in_sizes, int n_in,
                              void* d_out, int out_size, void* d_ws, size_t ws_size,
                              hipStream_t stream) {
    const float* x   = (const float*)d_in[0];
    const float* y   = (const float*)d_in[1];
    const float* Wq  = (const float*)d_in[2];
    const float* Wk  = (const float*)d_in[3];
    const float* Wv  = (const float*)d_in[4];
    const float* rlh = (const float*)d_in[5];
    const float* rlw = (const float*)d_in[6];
    float* out = (float*)d_out;

    float* qkv = (float*)d_ws;        // q | k | v, 4 MB each, contiguous
    float* q = qkv;
    float* k = qkv + (1 << 20);
    float* v = qkv + (2 << 20);

    // MEASUREMENT: reps=12 on proj only — lifts it past the ~42us profiler
    // cutoff whether healthy (~4us/rep -> ~50us) or sick (~30us/rep ->
    // ~360us), so next round's reps=1 decision is counter-driven.
    proj_kernel<<<768, 256, 0, stream>>>(x, y, Wq, Wk, Wv, qkv, 12);
    attn_kernel<<<1024, 256, 0, stream>>>(q, k, v, rlh, rlw, out);
}

// Round 12
// 120.800 us; speedup vs baseline: 11.1334x; 11.1334x over previous
//
#include <hip/hip_runtime.h>

#define HW 4096   // 64*64 pixels per (b,c) image

typedef float f4 __attribute__((ext_vector_type(4)));

// ---------------------------------------------------------------------------
// proj v11: q=Wq@x, k=Wk@x, v=Wv@y.
// R11 verdict: the 16-KB (2^14) channel stride defeats L1/L2 set indexing —
// v7/v9 both measured 163-165 MB FETCH/rep (13x compulsory), VALUBusy 2.6%,
// zero LDS conflicts. Fix = touch global memory ONCE, contiguously:
//  * block = 256-px tile, staged to LDS: each wave-instr reads 1 KB
//    CONTIGUOUS of one channel (8 full lines, full set spread).
//  * wave pulls its 64-px slice into xv[64] VGPRs (dense ds_read_b32,
//    conflict-free); all FMA operands come from registers.
//  * weights via wave-uniform s_load (R7: SGPR=112 proved this path);
//    32 couts/block fully unrolled = 2048 v_fmac, ~8 KB code, ~90 VGPR.
//  * stores: 256 B contiguous per cout row = full lines (no write-allocate).
// grid = 384 = 3 fams x 2 co-halves x 64 tiles; blockIdx%8 = tile%8 so
// same-tile blocks (q,k share x) land on the same XCD's L2.
// Input HBM traffic: x 2x + y 1x = 12 MB compulsory; writes 12 MB full-line.
// ---------------------------------------------------------------------------
__global__ __launch_bounds__(256) void proj_kernel(
    const float* __restrict__ x, const float* __restrict__ y,
    const float* __restrict__ Wq, const float* __restrict__ Wk,
    const float* __restrict__ Wv,
    float* __restrict__ qkv)     // q | k | v, each 1<<20 floats
{
    __shared__ float xs[64 * 256];           // 64 KB: [cin][256 px]
    const int t    = threadIdx.x;
    const int fs   = blockIdx.x >> 6;        // fam*2 + half, 0..5 (uniform)
    const int tile = blockIdx.x & 63;        // 256-px tile
    const int fam  = fs >> 1;                // 0=q 1=k 2=v
    const int r0   = (fs & 1) * 32;          // cout base (uniform)
    const int b    = tile >> 4;              // batch image
    const int pp0  = (tile & 15) * 256;      // pixel offset within image

    const float* W   = (fam == 0) ? Wq : (fam == 1) ? Wk : Wv;   // uniform
    const float* src = (fam == 2) ? y : x;                       // uniform
    const float* sb  = src + (size_t)b * 64 * HW + pp0;

    // stage: 16 f4/thread; each wave-instruction reads 1 KB contiguous of
    // ONE channel (fi>>6 is wave-uniform) -> 8 full lines per instr.
#pragma unroll
    for (int s = 0; s < 16; ++s) {
        const int fi  = s * 256 + t;
        const int cin = fi >> 6, c4 = fi & 63;
        const f4 v = *(const f4*)&sb[cin * HW + c4 * 4];
        *(f4*)&xs[cin * 256 + c4 * 4] = v;
    }
    __syncthreads();

    // compute: wave = 64 px x 32 couts; inputs register-resident.
    const int wv = t >> 6, lane = t & 63;
    float xv[64];
#pragma unroll
    for (int c = 0; c < 64; ++c)
        xv[c] = xs[c * 256 + wv * 64 + lane];   // dense, conflict-free

    float* dst = qkv + ((size_t)fam << 20)
                     + ((size_t)b * 64 + r0) * HW + pp0 + wv * 64 + lane;
#pragma unroll
    for (int j = 0; j < 32; ++j) {
        const float* wr = W + (r0 + j) * 64;    // uniform -> s_load
        float acc = 0.f;
#pragma unroll
        for (int c = 0; c < 64; ++c)
            acc = fmaf(wr[c], xv[c], acc);
        dst[(size_t)j * HW] = acc;              // 256 B contiguous per row
    }
}

// ---------------------------------------------------------------------------
// attn (final, R9-measured ~7.9us): per-channel 7x7 window attention,
// LDS k/v tile with zero halo. Inner op: fma + exp2 + add + fma. No clamp
// (|log2e*q*(k+bias)| < ~100 << 128 -> exp2 overflow impossible).
// grid = 1024 (b, c, 16-row band), block 256, thread = 4 px.
// ---------------------------------------------------------------------------
__global__ __launch_bounds__(256) void attn_kernel(
    const float* __restrict__ qg, const float* __restrict__ kg,
    const float* __restrict__ vg,
    const float* __restrict__ rel_h, const float* __restrict__ rel_w,
    float* __restrict__ out)
{
    __shared__ float kT[22 * 72];
    __shared__ float vT[22 * 72];

    const int blk = blockIdx.x;
    const int bc  = blk >> 2;            // b*64 + c
    const int h0  = (blk & 3) << 4;
    const int c   = bc & 63;
    const int t   = threadIdx.x;

    const float* kimg = kg + (size_t)bc * HW;
    const float* vimg = vg + (size_t)bc * HW;
    const f4 z4 = {0.f, 0.f, 0.f, 0.f};

    if (t < 88) {                        // horizontal halo zero
        const int row = t >> 2, side = (t >> 1) & 1, arr = t & 1;
        float* dstl = arr ? vT : kT;
        *(f4*)&dstl[row * 72 + side * 68] = z4;
    }
#pragma unroll
    for (int j = 0; j < 2; ++j) {        // interior: 22 rows x 16 f4 chunks
        const int idx = j * 256 + t;
        if (idx < 352) {
            const int row = idx >> 4, ch = idx & 15;
            const int hy = h0 - 3 + row;
            const bool rv = ((unsigned)hy < 64u);
            const f4 kv = rv ? *(const f4*)&kimg[hy * 64 + ch * 4] : z4;
            const f4 vv = rv ? *(const f4*)&vimg[hy * 64 + ch * 4] : z4;
            *(f4*)&kT[row * 72 + ch * 4 + 4] = kv;
            *(f4*)&vT[row * 72 + ch * 4 + 4] = vv;
        }
    }
    __syncthreads();

    const int r  = t >> 4;               // 0..15
    const int w0 = (t & 15) << 2;
    const int h  = h0 + r;

    const float LOG2E = 1.4426950408889634f;
    const f4 qv = *(const f4*)&qg[(size_t)bc * HW + h * 64 + w0];
    float qe[4];
#pragma unroll
    for (int p = 0; p < 4; ++p) qe[p] = qv[p] * LOG2E;

    float qb[7][4];
    if (c < 32) {
#pragma unroll
        for (int a = 0; a < 7; ++a) {
            const float bb = rel_h[c * 7 + a];
#pragma unroll
            for (int p = 0; p < 4; ++p) qb[a][p] = qe[p] * bb;
        }
    } else {
#pragma unroll
        for (int j = 0; j < 7; ++j) {
            const float bb = rel_w[(c - 32) * 7 + j];
#pragma unroll
            for (int p = 0; p < 4; ++p) qb[j][p] = qe[p] * bb;
        }
    }

    float l[4] = {0.f, 0.f, 0.f, 0.f};
    float o[4] = {0.f, 0.f, 0.f, 0.f};

    if (c < 32) {
#pragma unroll
        for (int a = 0; a < 7; ++a) {
            const int ro = (r + a) * 72 + w0;
            const f4 k0 = *(const f4*)&kT[ro];
            const f4 k1 = *(const f4*)&kT[ro + 4];
            const f4 k2 = *(const f4*)&kT[ro + 8];
            const f4 v0 = *(const f4*)&vT[ro];
            const f4 v1 = *(const f4*)&vT[ro + 4];
            const f4 v2 = *(const f4*)&vT[ro + 8];
            const float kw[12] = {k0[0], k0[1], k0[2], k0[3], k1[0], k1[1], k1[2], k1[3],
                                  k2[0], k2[1], k2[2], k2[3]};
            const float vw[12] = {v0[0], v0[1], v0[2], v0[3], v1[0], v1[1], v1[2], v1[3],
                                  v2[0], v2[1], v2[2], v2[3]};
#pragma unroll
            for (int b2 = 0; b2 < 7; ++b2)
#pragma unroll
                for (int p = 0; p < 4; ++p) {
                    const float s = fmaf(qe[p], kw[p + b2 + 1], qb[a][p]);
                    const float e = __builtin_amdgcn_exp2f(s);
                    l[p] += e;
                    o[p] = fmaf(e, vw[p + b2 + 1], o[p]);
                }
        }
    } else {
#pragma unroll
        for (int a = 0; a < 7; ++a) {
            const int ro = (r + a) * 72 + w0;
            const f4 k0 = *(const f4*)&kT[ro];
            const f4 k1 = *(const f4*)&kT[ro + 4];
            const f4 k2 = *(const f4*)&kT[ro + 8];
            const f4 v0 = *(const f4*)&vT[ro];
            const f4 v1 = *(const f4*)&vT[ro + 4];
            const f4 v2 = *(const f4*)&vT[ro + 8];
            const float kw[12] = {k0[0], k0[1], k0[2], k0[3], k1[0], k1[1], k1[2], k1[3],
                                  k2[0], k2[1], k2[2], k2[3]};
            const float vw[12] = {v0[0], v0[1], v0[2], v0[3], v1[0], v1[1], v1[2], v1[3],
                                  v2[0], v2[1], v2[2], v2[3]};
#pragma unroll
            for (int b2 = 0; b2 < 7; ++b2)
#pragma unroll
                for (int p = 0; p < 4; ++p) {
                    const float s = fmaf(qe[p], kw[p + b2 + 1], qb[b2][p]);
                    const float e = __builtin_amdgcn_exp2f(s);
                    l[p] += e;
                    o[p] = fmaf(e, vw[p + b2 + 1], o[p]);
                }
        }
    }

    f4 res;
#pragma unroll
    for (int p = 0; p < 4; ++p)
        res[p] = o[p] * __builtin_amdgcn_rcpf(l[p]);
    *(f4*)&out[(size_t)bc * HW + h * 64 + w0] = res;
}

// ---------------------------------------------------------------------------
extern "C" void kernel_launch(void* const* d_in, const int* in_sizes, int n_in,
                              void* d_out, int out_size, void* d_ws, size_t ws_size,
                              hipStream_t stream) {
    const float* x   = (const float*)d_in[0];
    const float* y   = (const float*)d_in[1];
    const float* Wq  = (const float*)d_in[2];
    const float* Wk  = (const float*)d_in[3];
    const float* Wv  = (const float*)d_in[4];
    const float* rlh = (const float*)d_in[5];
    const float* rlw = (const float*)d_in[6];
    float* out = (float*)d_out;

    float* qkv = (float*)d_ws;        // q | k | v, 4 MB each, contiguous
    float* q = qkv;
    float* k = qkv + (1 << 20);
    float* v = qkv + (2 << 20);

    proj_kernel<<<384, 256, 0, stream>>>(x, y, Wq, Wk, Wv, qkv);
    attn_kernel<<<1024, 256, 0, stream>>>(q, k, v, rlh, rlw, out);
}

// Round 13
// 102.597 us; speedup vs baseline: 13.1088x; 1.1774x over previous
//
#include <hip/hip_runtime.h>

#define HW 4096   // 64*64 pixels per (b,c) image

typedef float f4 __attribute__((ext_vector_type(4)));

// ---------------------------------------------------------------------------
// proj v12: q=Wq@x, k=Wk@x, v=Wv@y.
// R12 verdict: v11 was traffic-clean (FETCH 4.6MB, WRITE 12MB, 0 conflicts)
// but latency-bound at 1.5 waves/SIMD (VALUBusy 11%, Occ 11.5%). v12 keeps
// the clean-traffic structure and doubles occupancy + halves the chain:
//  * 64-px tile -> 16KB LDS; grid = 3 fams x 256 tiles = 768 blocks
//    -> 3 blocks/CU resident -> 3 waves/SIMD (v11: 1.5).
//  * wave = 64 px (lane=px) x 16 couts; xv[64] register-resident via
//    ds_read_b32 (v11-proven: zero bank conflicts).
//  * weight row uniform-per-wave but wave-id-dependent: forced scalar via
//    __builtin_amdgcn_readfirstlane -> s_load (R7-verified path).
//  * stores: 256B contiguous per cout row (full lines, no write-allocate).
// Traffic: x staged 2x + y 1x (L3 absorbs re-read), writes 12MB compulsory.
// ---------------------------------------------------------------------------
__global__ __launch_bounds__(256) void proj_kernel(
    const float* __restrict__ x, const float* __restrict__ y,
    const float* __restrict__ Wq, const float* __restrict__ Wk,
    const float* __restrict__ Wv,
    float* __restrict__ qkv)     // q | k | v, each 1<<20 floats
{
    __shared__ float xs[64 * 64];            // 16 KB: [cin][64 px]
    const int t    = threadIdx.x;
    const int fam  = blockIdx.x >> 8;        // 0=q 1=k 2=v (uniform)
    const int tile = blockIdx.x & 255;       // 64-px tile
    const int b    = tile >> 6;              // batch image
    const int pp0  = (tile & 63) * 64;       // pixel offset within image

    const float* W   = (fam == 0) ? Wq : (fam == 1) ? Wk : Wv;   // uniform
    const float* src = (fam == 2) ? y : x;                       // uniform
    const float* sb  = src + (size_t)b * 64 * HW + pp0;

    // stage: 1024 f4 = 64 cin x 16 f4-chunks; each wave-instr covers 4
    // channels x 256B contiguous each (full lines). 4 f4 per thread.
#pragma unroll
    for (int s = 0; s < 4; ++s) {
        const int fi  = s * 256 + t;
        const int cin = fi >> 4, chq = fi & 15;
        const f4 v = *(const f4*)&sb[cin * HW + chq * 4];
        *(f4*)&xs[cin * 64 + chq * 4] = v;   // v11-proven: 0 conflicts
    }
    __syncthreads();

    // pull this lane's pixel column into registers (dense, 2/bank = free)
    const int wv = t >> 6, lane = t & 63;
    float xv[64];
#pragma unroll
    for (int c = 0; c < 64; ++c)
        xv[c] = xs[c * 64 + lane];

    // compute: wave wv handles couts wv*16 .. wv*16+15
    float* dst = qkv + ((size_t)fam << 20)
                     + ((size_t)b * 64 + wv * 16) * HW + pp0 + lane;
#pragma unroll
    for (int j = 0; j < 16; ++j) {
        // row offset is wave-uniform by construction; readfirstlane makes it
        // PROVABLY uniform to the compiler -> weights go through s_load.
        const int off = __builtin_amdgcn_readfirstlane((wv * 16 + j) * 64);
        const float* wr = W + off;
        float acc = 0.f;
#pragma unroll
        for (int c = 0; c < 64; ++c)
            acc = fmaf(wr[c], xv[c], acc);
        dst[(size_t)j * HW] = acc;           // 256 B contiguous
    }
}

// ---------------------------------------------------------------------------
// attn (final, R9-measured ~7.9us): per-channel 7x7 window attention,
// LDS k/v tile with zero halo. Inner op: fma + exp2 + add + fma. No clamp
// (|log2e*q*(k+bias)| < ~100 << 128 -> exp2 overflow impossible).
// grid = 1024 (b, c, 16-row band), block 256, thread = 4 px.
// ---------------------------------------------------------------------------
__global__ __launch_bounds__(256) void attn_kernel(
    const float* __restrict__ qg, const float* __restrict__ kg,
    const float* __restrict__ vg,
    const float* __restrict__ rel_h, const float* __restrict__ rel_w,
    float* __restrict__ out)
{
    __shared__ float kT[22 * 72];
    __shared__ float vT[22 * 72];

    const int blk = blockIdx.x;
    const int bc  = blk >> 2;            // b*64 + c
    const int h0  = (blk & 3) << 4;
    const int c   = bc & 63;
    const int t   = threadIdx.x;

    const float* kimg = kg + (size_t)bc * HW;
    const float* vimg = vg + (size_t)bc * HW;
    const f4 z4 = {0.f, 0.f, 0.f, 0.f};

    if (t < 88) {                        // horizontal halo zero
        const int row = t >> 2, side = (t >> 1) & 1, arr = t & 1;
        float* dstl = arr ? vT : kT;
        *(f4*)&dstl[row * 72 + side * 68] = z4;
    }
#pragma unroll
    for (int j = 0; j < 2; ++j) {        // interior: 22 rows x 16 f4 chunks
        const int idx = j * 256 + t;
        if (idx < 352) {
            const int row = idx >> 4, ch = idx & 15;
            const int hy = h0 - 3 + row;
            const bool rv = ((unsigned)hy < 64u);
            const f4 kv = rv ? *(const f4*)&kimg[hy * 64 + ch * 4] : z4;
            const f4 vv = rv ? *(const f4*)&vimg[hy * 64 + ch * 4] : z4;
            *(f4*)&kT[row * 72 + ch * 4 + 4] = kv;
            *(f4*)&vT[row * 72 + ch * 4 + 4] = vv;
        }
    }
    __syncthreads();

    const int r  = t >> 4;               // 0..15
    const int w0 = (t & 15) << 2;
    const int h  = h0 + r;

    const float LOG2E = 1.4426950408889634f;
    const f4 qv = *(const f4*)&qg[(size_t)bc * HW + h * 64 + w0];
    float qe[4];
#pragma unroll
    for (int p = 0; p < 4; ++p) qe[p] = qv[p] * LOG2E;

    float qb[7][4];
    if (c < 32) {
#pragma unroll
        for (int a = 0; a < 7; ++a) {
            const float bb = rel_h[c * 7 + a];
#pragma unroll
            for (int p = 0; p < 4; ++p) qb[a][p] = qe[p] * bb;
        }
    } else {
#pragma unroll
        for (int j = 0; j < 7; ++j) {
            const float bb = rel_w[(c - 32) * 7 + j];
#pragma unroll
            for (int p = 0; p < 4; ++p) qb[j][p] = qe[p] * bb;
        }
    }

    float l[4] = {0.f, 0.f, 0.f, 0.f};
    float o[4] = {0.f, 0.f, 0.f, 0.f};

    if (c < 32) {
#pragma unroll
        for (int a = 0; a < 7; ++a) {
            const int ro = (r + a) * 72 + w0;
            const f4 k0 = *(const f4*)&kT[ro];
            const f4 k1 = *(const f4*)&kT[ro + 4];
            const f4 k2 = *(const f4*)&kT[ro + 8];
            const f4 v0 = *(const f4*)&vT[ro];
            const f4 v1 = *(const f4*)&vT[ro + 4];
            const f4 v2 = *(const f4*)&vT[ro + 8];
            const float kw[12] = {k0[0], k0[1], k0[2], k0[3], k1[0], k1[1], k1[2], k1[3],
                                  k2[0], k2[1], k2[2], k2[3]};
            const float vw[12] = {v0[0], v0[1], v0[2], v0[3], v1[0], v1[1], v1[2], v1[3],
                                  v2[0], v2[1], v2[2], v2[3]};
#pragma unroll
            for (int b2 = 0; b2 < 7; ++b2)
#pragma unroll
                for (int p = 0; p < 4; ++p) {
                    const float s = fmaf(qe[p], kw[p + b2 + 1], qb[a][p]);
                    const float e = __builtin_amdgcn_exp2f(s);
                    l[p] += e;
                    o[p] = fmaf(e, vw[p + b2 + 1], o[p]);
                }
        }
    } else {
#pragma unroll
        for (int a = 0; a < 7; ++a) {
            const int ro = (r + a) * 72 + w0;
            const f4 k0 = *(const f4*)&kT[ro];
            const f4 k1 = *(const f4*)&kT[ro + 4];
            const f4 k2 = *(const f4*)&kT[ro + 8];
            const f4 v0 = *(const f4*)&vT[ro];
            const f4 v1 = *(const f4*)&vT[ro + 4];
            const f4 v2 = *(const f4*)&vT[ro + 8];
            const float kw[12] = {k0[0], k0[1], k0[2], k0[3], k1[0], k1[1], k1[2], k1[3],
                                  k2[0], k2[1], k2[2], k2[3]};
            const float vw[12] = {v0[0], v0[1], v0[2], v0[3], v1[0], v1[1], v1[2], v1[3],
                                  v2[0], v2[1], v2[2], v2[3]};
#pragma unroll
            for (int b2 = 0; b2 < 7; ++b2)
#pragma unroll
                for (int p = 0; p < 4; ++p) {
                    const float s = fmaf(qe[p], kw[p + b2 + 1], qb[b2][p]);
                    const float e = __builtin_amdgcn_exp2f(s);
                    l[p] += e;
                    o[p] = fmaf(e, vw[p + b2 + 1], o[p]);
                }
        }
    }

    f4 res;
#pragma unroll
    for (int p = 0; p < 4; ++p)
        res[p] = o[p] * __builtin_amdgcn_rcpf(l[p]);
    *(f4*)&out[(size_t)bc * HW + h * 64 + w0] = res;
}

// ---------------------------------------------------------------------------
extern "C" void kernel_launch(void* const* d_in, const int* in_sizes, int n_in,
                              void* d_out, int out_size, void* d_ws, size_t ws_size,
                              hipStream_t stream) {
    const float* x   = (const float*)d_in[0];
    const float* y   = (const float*)d_in[1];
    const float* Wq  = (const float*)d_in[2];
    const float* Wk  = (const float*)d_in[3];
    const float* Wv  = (const float*)d_in[4];
    const float* rlh = (const float*)d_in[5];
    const float* rlw = (const float*)d_in[6];
    float* out = (float*)d_out;

    float* qkv = (float*)d_ws;        // q | k | v, 4 MB each, contiguous
    float* q = qkv;
    float* k = qkv + (1 << 20);
    float* v = qkv + (2 << 20);

    proj_kernel<<<768, 256, 0, stream>>>(x, y, Wq, Wk, Wv, qkv);
    attn_kernel<<<1024, 256, 0, stream>>>(q, k, v, rlh, rlw, out);
}